// Round 6
// baseline (125.550 us; speedup 1.0000x reference)
//
#include <hip/hip_runtime.h>
#include <stdint.h>

// InterGate: B=1, C=192, H=W=96.  Flash-attention formulation:
//   Q = (latent*w4)^T, K = refined^T, V = (latent*w4)^T   (all [9216, 192])
//   out = refined*w5 + (softmax(Q K^T) V)^T
// Round-6 structure (model: time = iters x (fixed ~3k cyc + LDS cyc)):
//   * 128-key iterations -> 10-11 barriers per block (r3 had 20.6, r5 had 41
//     effective): halves the dominant per-iteration fixed cost
//   * K in LDS (2 x 48KB dbuf), V from global (L1/L2-served, separate pipe,
//     overlaps LDS reads; validated r5), 2 V-groups pipelined in registers
//   * 8 waves x 32 q (32x32x16 swapped-QK), ~212 unified regs -> 2 waves/SIMD
//   * permuted-V rows (P B-frag = cvt_pk words, zero shuffle), exp2-direct,
//     no-max softmax, KS=7 key splits (grid 252, every CU <= 1 block)

#define NQ 9216
#define NC 192
#define FR 1769472      // 9216*192 elements per fragment array
#define LOG2E 1.4426950408889634f
#define M0L 36.06737602f   // 25 * log2(e)

typedef short    bfrag  __attribute__((ext_vector_type(8)));   // 8 bf16
typedef _Float16 hfrag  __attribute__((ext_vector_type(8)));   // 8 f16
typedef short    sfrag4 __attribute__((ext_vector_type(4)));   // 4 bf16 (8B)
typedef float    facc16 __attribute__((ext_vector_type(16)));  // 32x32 accum

__device__ __forceinline__ short f2bf(float x) {
    uint32_t u = __builtin_bit_cast(uint32_t, x);
    u = (u + 0x7fffu + ((u >> 16) & 1u)) >> 16;
    return (short)u;
}
__device__ __forceinline__ float bf2f(short s) {
    uint32_t u = ((uint32_t)(uint16_t)s) << 16;
    return __builtin_bit_cast(float, u);
}
__device__ __forceinline__ int cvtpk_bf16(float lo, float hi) {
    int r;
    asm("v_cvt_pk_bf16_f32 %0, %1, %2" : "=v"(r) : "v"(lo), "v"(hi));
    return r;
}
__device__ __forceinline__ float exp2_raw(float x) {   // 2^x via v_exp_f32
    float r;
    asm("v_exp_f32 %0, %1" : "=v"(r) : "v"(x));
    return r;
}
__device__ __forceinline__ bfrag words_to_frag(int w0, int w1, int w2, int w3) {
    union { int i[4]; bfrag f; } u;
    u.i[0] = w0; u.i[1] = w1; u.i[2] = w2; u.i[3] = w3;
    return u.f;
}
__device__ __forceinline__ void gload_lds16(const void* g, void* l) {
    __builtin_amdgcn_global_load_lds(
        (__attribute__((address_space(1))) const void*)(uintptr_t)g,
        (__attribute__((address_space(3))) void*)(uint32_t)(uintptr_t)l,
        16, 0, 0);
}

// ---------------------------------------------------------------------------
// Prep: fragment-ordered arrays for 32x32x16 (l32=lane&31, h=lane>>5).
// Qf (f16, B-frag, pre-scaled by log2e):
//   [qw(288)][t(12)][lane][i8] = log2e * Q[qw*32+l32][t*16+h*8+i]
// Karr (f16, A-frag), per 128-key group g (24576 shorts = 48KB):
//   [g(72)][n2(4)][t(12)][lane][i8] = K[g*128+n2*32+l32][t*16+h*8+i]
// Varr (bf16, A-frag of V^T, PERMUTED key rows to match S' C/D order):
//   [g(72)][T(8)][cb(6)][lane][i8] = V[g*128+T*16+(i&3)+8*(i>>2)+4*h][cb*32+l32]
// ---------------------------------------------------------------------------
__global__ __launch_bounds__(256) void InterGate_prep(
    const float* __restrict__ latent, const float* __restrict__ refined,
    const float* __restrict__ w4,
    short* __restrict__ Qf, short* __restrict__ Karr, short* __restrict__ Varr)
{
    const int wid  = blockIdx.x * 4 + (threadIdx.x >> 6);
    const int lane = threadIdx.x & 63;
    const int l32  = lane & 31, h = lane >> 5;

    if (wid < 3456) {                       // Q fragments (latent*w4*log2e), f16
        const int qw = wid / 12, t = wid % 12;
        const int q  = qw * 32 + l32;
        const int c0 = t * 16 + h * 8;
        hfrag hv;
        #pragma unroll
        for (int i = 0; i < 8; i++) {
            size_t idx = (size_t)(c0 + i) * NQ + q;
            hv[i] = (_Float16)(latent[idx] * w4[idx] * LOG2E);
        }
        *(hfrag*)(void*)(Qf + ((size_t)wid * 64 + lane) * 8) = hv;
    } else if (wid < 6912) {                // K fragments (refined), f16
        const int u = wid - 3456;           // u = g*48 + n2*12 + t
        const int g = u / 48, r = u % 48;
        const int n2 = r / 12, t = r % 12;
        const int key = g * 128 + n2 * 32 + l32;
        const int c0  = t * 16 + h * 8;
        hfrag hv;
        #pragma unroll
        for (int i = 0; i < 8; i++) {
            size_t idx = (size_t)(c0 + i) * NQ + key;
            hv[i] = (_Float16)refined[idx];
        }
        *(hfrag*)(void*)(Karr + ((size_t)u * 64 + lane) * 8) = hv;
    } else {                                // V fragments (latent*w4), bf16, permuted
        const int u = wid - 6912;           // u = g*48 + T*6 + cb
        const int g = u / 48, r = u % 48;
        const int T = r / 6, cb = r % 6;
        const int c  = cb * 32 + l32;
        const int k0 = g * 128 + T * 16 + 4 * h;
        bfrag bv;
        #pragma unroll
        for (int i = 0; i < 8; i++) {
            const int row = k0 + (i & 3) + 8 * (i >> 2);
            size_t idx = (size_t)c * NQ + row;
            bv[i] = f2bf(latent[idx] * w4[idx]);
        }
        *(bfrag*)(void*)(Varr + ((size_t)u * 64 + lane) * 8) = bv;
    }
}

// ---------------------------------------------------------------------------
// Flash: grid (36 q-tiles of 256, KS key-splits in 128-key units), 8 waves
// x 32 q.  K: 128-key tiles double-buffered in LDS (96KB).  V: global
// (L1-served, identical addresses across waves), 2 x 16-key groups in flight.
// One barrier per 128 keys.
// ---------------------------------------------------------------------------
__global__ __launch_bounds__(512, 2) void InterGate_flash(
    const short* __restrict__ Qf, const short* __restrict__ Karr,
    const short* __restrict__ Varr,
    short* __restrict__ Opart, float* __restrict__ l_ws, int KS)
{
    __shared__ __align__(16) short kbuf[2][24576];   // 2 x 48KB K (f16)

    const int tid  = threadIdx.x;
    const int lane = tid & 63, w = tid >> 6;
    const int l32  = lane & 31, h = lane >> 5;
    const int qt   = blockIdx.x, ks = blockIdx.y;

    // key range in 128-key units (72 total)
    const int base = 72 / KS, rem = 72 % KS;
    const int start = ks * base + (ks < rem ? ks : rem);
    const int cnt   = base + (ks < rem ? 1 : 0);

    // Q B-frags in registers (48 VGPR)
    const int qw = qt * 8 + w;
    hfrag qf[12];
    #pragma unroll
    for (int t = 0; t < 12; t++)
        qf[t] = *(const hfrag*)(const void*)(Qf + (((size_t)qw * 12 + t) * 64 + lane) * 8);

    facc16 O[6];
    #pragma unroll
    for (int cb = 0; cb < 6; cb++)
        #pragma unroll
        for (int j = 0; j < 16; j++) O[cb][j] = 0.f;
    float lsum = 0.f;

    {   // stage K tile 0: 48 x 1KB chunks, 6 per wave
        const char* src = (const char*)(Karr + (size_t)start * 24576) + w * 6144 + lane * 16;
        char* dst = (char*)&kbuf[0][0] + w * 6144;
        #pragma unroll
        for (int j = 0; j < 6; j++) gload_lds16(src + j * 1024, dst + j * 1024);
    }
    // preload first two 16-key V groups (flat T-stream index f)
    const int fend = (start + cnt) * 8;
    bfrag vgA[6], vgB[6];
    {
        const char* vb = (const char*)Varr + (size_t)start * 49152 + lane * 16;
        #pragma unroll
        for (int cb = 0; cb < 6; cb++) {
            vgA[cb] = *(const bfrag*)(const void*)(vb + cb * 1024);
            vgB[cb] = *(const bfrag*)(const void*)(vb + 6144 + cb * 1024);
        }
    }

    for (int kt = 0; kt < cnt; kt++) {
        __syncthreads();                       // kbuf[cur] staged (drains vmem)
        const int cur = kt & 1;
        if (kt + 1 < cnt) {                    // prefetch next K tile
            const char* src = (const char*)(Karr + (size_t)(start + kt + 1) * 24576) + w * 6144 + lane * 16;
            char* dst = (char*)&kbuf[cur ^ 1][0] + w * 6144;
            #pragma unroll
            for (int j = 0; j < 6; j++) gload_lds16(src + j * 1024, dst + j * 1024);
        }
        const short* kb = &kbuf[cur][0];
        const int f0 = (start + kt) * 8;       // this tile's first V group

        #pragma unroll
        for (int n2 = 0; n2 < 4; n2++) {
            // ---- S' = K Q: 32 keys x 32 queries (f16, single-term) ----
            facc16 S;
            #pragma unroll
            for (int j = 0; j < 16; j++) S[j] = 0.f;
            #pragma unroll
            for (int t = 0; t < 12; t++) {
                hfrag kf = *(const hfrag*)(const void*)(kb + (n2 * 12 + t) * 512 + lane * 8);
                S = __builtin_amdgcn_mfma_f32_32x32x16_f16(kf, qf[t], S, 0, 0, 0);
            }
            // S' layout: key = (j&3)+8*(j>>2)+4*h (lane-local), q = l32

            // ---- P = 2^(S' - M0L); tree-sum; pack (no cross-lane moves) ----
            float p[16];
            #pragma unroll
            for (int j = 0; j < 16; j++) p[j] = exp2_raw(S[j] - M0L);
            lsum += (((p[0]+p[1])+(p[2]+p[3]))+((p[4]+p[5])+(p[6]+p[7])))
                  + (((p[8]+p[9])+(p[10]+p[11]))+((p[12]+p[13])+(p[14]+p[15])));
            int cp[8];
            #pragma unroll
            for (int a = 0; a < 8; a++) cp[a] = cvtpk_bf16(p[2 * a], p[2 * a + 1]);

            // ---- O^T += V^T P; refill the just-used V regs from f+2 ----
            {   // half A: V group f0 + n2*2
                bfrag pf = words_to_frag(cp[0], cp[1], cp[2], cp[3]);
                #pragma unroll
                for (int cb = 0; cb < 6; cb++)
                    O[cb] = __builtin_amdgcn_mfma_f32_32x32x16_bf16(vgA[cb], pf, O[cb], 0, 0, 0);
                const int fn = f0 + n2 * 2 + 2;
                if (fn < fend) {
                    const char* vb = (const char*)Varr + (size_t)fn * 6144 + lane * 16;
                    #pragma unroll
                    for (int cb = 0; cb < 6; cb++)
                        vgA[cb] = *(const bfrag*)(const void*)(vb + cb * 1024);
                }
            }
            {   // half B: V group f0 + n2*2 + 1
                bfrag pf = words_to_frag(cp[4], cp[5], cp[6], cp[7]);
                #pragma unroll
                for (int cb = 0; cb < 6; cb++)
                    O[cb] = __builtin_amdgcn_mfma_f32_32x32x16_bf16(vgB[cb], pf, O[cb], 0, 0, 0);
                const int fn = f0 + n2 * 2 + 3;
                if (fn < fend) {
                    const char* vb = (const char*)Varr + (size_t)fn * 6144 + lane * 16;
                    #pragma unroll
                    for (int cb = 0; cb < 6; cb++)
                        vgB[cb] = *(const bfrag*)(const void*)(vb + cb * 1024);
                }
            }
        }
    }

    // ---- epilogue: Opart[ks][q][c] (bf16, unnormalized) + l per query ----
    const int q0 = qt * 256 + w * 32 + l32;
    short* row = Opart + ((size_t)ks * NQ + q0) * NC;
    #pragma unroll
    for (int cb = 0; cb < 6; cb++) {
        #pragma unroll
        for (int g = 0; g < 4; g++) {
            const int c0 = cb * 32 + 8 * g + 4 * h;
            sfrag4 s4;
            #pragma unroll
            for (int r = 0; r < 4; r++) s4[r] = f2bf(O[cb][4 * g + r]);
            *(sfrag4*)(void*)(row + c0) = s4;
        }
    }
    float lt = lsum + __shfl_xor(lsum, 32);
    if (h == 0) l_ws[(size_t)ks * NQ + q0] = lt;
}

// ---------------------------------------------------------------------------
// Combine: sum KS partials (common scale), normalize, transpose via LDS,
// fused epilogue out = refined*w5 + ctx.  288 blocks x 32 queries.
// ---------------------------------------------------------------------------
__global__ __launch_bounds__(256) void InterGate_combine(
    const short* __restrict__ Opart, const float* __restrict__ l_ws,
    const float* __restrict__ refined, const float* __restrict__ w5,
    float* __restrict__ out, int KS)
{
    __shared__ float ctx[32][193];
    __shared__ float sInv[32];
    const int qt = blockIdx.x, tid = threadIdx.x;

    if (tid < 32) {
        const int q = qt * 32 + tid;
        float L = 0.f;
        for (int ks = 0; ks < KS; ks++) L += l_ws[(size_t)ks * NQ + q];
        sInv[tid] = 1.f / L;
    }
    __syncthreads();

    for (int u = tid; u < 768; u += 256) {
        const int ql = u / 24, c0 = (u % 24) * 8;
        float acc[8] = {0.f, 0.f, 0.f, 0.f, 0.f, 0.f, 0.f, 0.f};
        for (int ks = 0; ks < KS; ks++) {
            bfrag pk = *(const bfrag*)(const void*)&Opart[((size_t)ks * NQ + qt * 32 + ql) * NC + c0];
            #pragma unroll
            for (int j = 0; j < 8; j++) acc[j] += bf2f(pk[j]);
        }
        const float inv = sInv[ql];
        #pragma unroll
        for (int j = 0; j < 8; j++) ctx[ql][c0 + j] = acc[j] * inv;
    }
    __syncthreads();

    for (int u = tid; u < 6144; u += 256) {
        const int c = u / 32, qx = u % 32;
        size_t o = (size_t)c * NQ + qt * 32 + qx;
        out[o] = refined[o] * w5[o] + ctx[qx][c];
    }
}

// ---------------------------------------------------------------------------
extern "C" void kernel_launch(void* const* d_in, const int* in_sizes, int n_in,
                              void* d_out, int out_size, void* d_ws, size_t ws_size,
                              hipStream_t stream)
{
    (void)in_sizes; (void)n_in; (void)out_size;
    const float* latent  = (const float*)d_in[0];
    const float* refined = (const float*)d_in[1];
    const float* w4      = (const float*)d_in[2];
    const float* w5      = (const float*)d_in[3];
    float* out = (float*)d_out;

    short* Qf   = (short*)d_ws;
    short* Karr = Qf + FR;
    short* Varr = Karr + FR;
    const size_t basebytes = (size_t)3 * FR * 2;

    // KS=7 -> grid 252 (every CU <= 1 block); fallbacks if ws is small
    const int opts[4] = {7, 4, 2, 1};
    int KS = 0;
    for (int i = 0; i < 4; i++) {
        size_t need = basebytes + (size_t)opts[i] * ((size_t)NQ * NC * 2 + (size_t)NQ * 4);
        if (need <= ws_size) { KS = opts[i]; break; }
    }
    if (KS == 0) return;

    short* Opart = (short*)((char*)d_ws + basebytes);
    float* l_ws  = (float*)((char*)d_ws + basebytes + (size_t)KS * NQ * NC * 2);

    InterGate_prep<<<2592, 256, 0, stream>>>(latent, refined, w4, Qf, Karr, Varr);
    dim3 fg(36, KS);
    InterGate_flash<<<fg, 512, 0, stream>>>(Qf, Karr, Varr, Opart, l_ws, KS);
    InterGate_combine<<<288, 256, 0, stream>>>(Opart, l_ws, refined, w5, out, KS);
}

// Round 7
// 96.711 us; speedup vs baseline: 1.2982x; 1.2982x over previous
//
#include <hip/hip_runtime.h>
#include <stdint.h>

// InterGate: B=1, C=192, H=W=96.  Flash-attention formulation:
//   Q = (latent*w4)^T, K = refined^T, V = (latent*w4)^T   (all [9216, 192])
//   out = refined*w5 + (softmax(Q K^T) V)^T
// Round-7: r3's data layout (K f16 + V bf16 both in LDS, 64-key tiles,
// 8 waves x 32 q) + the T3/T4/T5 pipelined schedule:
//   * 3 LDS buffers x 48KB (144KB), staged 2 tiles ahead via global_load_lds
//   * raw s_barrier + COUNTED s_waitcnt vmcnt(6) at tile boundaries (never
//     drain to 0 mid-loop) -> staging overlaps the whole compute phase
//   * s_setprio(1) around MFMA clusters
//   * validated math kept: f16 single-term QK (swapped operands -> key axis
//     lane-local), no-max softmax P=2^(S-M0L), permuted-V rows so the P
//     B-frag is exactly the cvt_pk word sequence (zero cross-lane moves)

#define NQ 9216
#define NC 192
#define FR 1769472      // 9216*192 elements per fragment array
#define LOG2E 1.4426950408889634f
#define M0L 36.06737602f   // 25 * log2(e)

typedef short    bfrag  __attribute__((ext_vector_type(8)));   // 8 bf16
typedef _Float16 hfrag  __attribute__((ext_vector_type(8)));   // 8 f16
typedef short    sfrag4 __attribute__((ext_vector_type(4)));   // 4 bf16 (8B)
typedef float    facc16 __attribute__((ext_vector_type(16)));  // 32x32 accum

__device__ __forceinline__ short f2bf(float x) {
    uint32_t u = __builtin_bit_cast(uint32_t, x);
    u = (u + 0x7fffu + ((u >> 16) & 1u)) >> 16;
    return (short)u;
}
__device__ __forceinline__ float bf2f(short s) {
    uint32_t u = ((uint32_t)(uint16_t)s) << 16;
    return __builtin_bit_cast(float, u);
}
__device__ __forceinline__ int cvtpk_bf16(float lo, float hi) {
    int r;
    asm("v_cvt_pk_bf16_f32 %0, %1, %2" : "=v"(r) : "v"(lo), "v"(hi));
    return r;
}
__device__ __forceinline__ float exp2_raw(float x) {   // 2^x via v_exp_f32
    float r;
    asm("v_exp_f32 %0, %1" : "=v"(r) : "v"(x));
    return r;
}
__device__ __forceinline__ bfrag words_to_frag(int w0, int w1, int w2, int w3) {
    union { int i[4]; bfrag f; } u;
    u.i[0] = w0; u.i[1] = w1; u.i[2] = w2; u.i[3] = w3;
    return u.f;
}
__device__ __forceinline__ void gload_lds16(const void* g, void* l) {
    __builtin_amdgcn_global_load_lds(
        (__attribute__((address_space(1))) const void*)(uintptr_t)g,
        (__attribute__((address_space(3))) void*)(uint32_t)(uintptr_t)l,
        16, 0, 0);
}

// ---------------------------------------------------------------------------
// Prep: fragment-ordered arrays for 32x32x16 (l32=lane&31, h=lane>>5).
// Qf (f16, B-frag, pre-scaled by log2e):
//   [qw(288)][t(12)][lane][i8] = log2e * Q[qw*32+l32][t*16+h*8+i]
// KV per 64-key group g (24576 shorts = 48KB), 144 groups:
//  [0]     K (f16, A-frag): [n2(2)][t(12)][lane][i8] = K[g*64+n2*32+l32][t*16+h*8+i]
//  [12288] V (bf16, A-frag of V^T, PERMUTED key rows matching S' C/D order):
//          [T(4)][cb(6)][lane][i8] = V[g*64+T*16+(i&3)+8*(i>>2)+4*h][cb*32+l32]
// ---------------------------------------------------------------------------
__global__ __launch_bounds__(256) void InterGate_prep(
    const float* __restrict__ latent, const float* __restrict__ refined,
    const float* __restrict__ w4,
    short* __restrict__ Qf, short* __restrict__ KV)
{
    const int wid  = blockIdx.x * 4 + (threadIdx.x >> 6);
    const int lane = threadIdx.x & 63;
    const int l32  = lane & 31, h = lane >> 5;

    if (wid < 3456) {                       // Q fragments (latent*w4*log2e), f16
        const int qw = wid / 12, t = wid % 12;
        const int q  = qw * 32 + l32;
        const int c0 = t * 16 + h * 8;
        hfrag hv;
        #pragma unroll
        for (int i = 0; i < 8; i++) {
            size_t idx = (size_t)(c0 + i) * NQ + q;
            hv[i] = (_Float16)(latent[idx] * w4[idx] * LOG2E);
        }
        *(hfrag*)(void*)(Qf + ((size_t)wid * 64 + lane) * 8) = hv;
    } else if (wid < 6912) {                // K fragments (refined), f16
        const int u = wid - 3456;           // u = g*24 + n2*12 + t
        const int g = u / 24, r = u % 24;
        const int n2 = r / 12, t = r % 12;
        const int key = g * 64 + n2 * 32 + l32;
        const int c0  = t * 16 + h * 8;
        hfrag hv;
        #pragma unroll
        for (int i = 0; i < 8; i++) {
            size_t idx = (size_t)(c0 + i) * NQ + key;
            hv[i] = (_Float16)refined[idx];
        }
        *(hfrag*)(void*)(KV + (size_t)g * 24576 + ((n2 * 12 + t) * 64 + lane) * 8) = hv;
    } else {                                // V fragments (latent*w4), bf16, permuted
        const int u = wid - 6912;           // u = g*24 + T*6 + cb
        const int g = u / 24, r = u % 24;
        const int T = r / 6, cb = r % 6;
        const int c  = cb * 32 + l32;
        const int k0 = g * 64 + T * 16 + 4 * h;
        bfrag bv;
        #pragma unroll
        for (int i = 0; i < 8; i++) {
            const int row = k0 + (i & 3) + 8 * (i >> 2);
            size_t idx = (size_t)c * NQ + row;
            bv[i] = f2bf(latent[idx] * w4[idx]);
        }
        *(bfrag*)(void*)(KV + (size_t)g * 24576 + 12288 + ((T * 6 + cb) * 64 + lane) * 8) = bv;
    }
}

// ---------------------------------------------------------------------------
// Flash: grid (36 q-tiles of 256, KS key-splits in 64-key units), 8 waves
// x 32 q.  Triple-buffered 48KB K|V tiles, staging 2 tiles ahead, one raw
// s_barrier + counted vmcnt per tile.
// ---------------------------------------------------------------------------
__device__ __forceinline__ void stage48(const short* KV, int g, char* dstb,
                                        int w, int lane) {
    const char* src = (const char*)(KV + (size_t)g * 24576) + w * 6144 + lane * 16;
    char* dst = dstb + w * 6144;            // wave-uniform base (+lane*16 in HW)
    #pragma unroll
    for (int j = 0; j < 6; j++) gload_lds16(src + j * 1024, dst + j * 1024);
}

__global__ __launch_bounds__(512, 2) void InterGate_flash(
    const short* __restrict__ Qf, const short* __restrict__ KV,
    short* __restrict__ Opart, float* __restrict__ l_ws, int KS)
{
    __shared__ __align__(16) short kv[3][24576];   // 3 x 48KB: K(f16) | V(bf16)

    const int tid  = threadIdx.x;
    const int lane = tid & 63, w = tid >> 6;
    const int l32  = lane & 31, h = lane >> 5;
    const int qt   = blockIdx.x, ks = blockIdx.y;

    // key range in 64-key units (144 total)
    const int base = 144 / KS, rem = 144 % KS;
    const int start = ks * base + (ks < rem ? ks : rem);
    const int cnt   = base + (ks < rem ? 1 : 0);

    // Q B-frags in registers (48 VGPR)
    const int qw = qt * 8 + w;
    hfrag qf[12];
    #pragma unroll
    for (int t = 0; t < 12; t++)
        qf[t] = *(const hfrag*)(const void*)(Qf + (((size_t)qw * 12 + t) * 64 + lane) * 8);

    facc16 O[6];
    #pragma unroll
    for (int cb = 0; cb < 6; cb++)
        #pragma unroll
        for (int j = 0; j < 16; j++) O[cb][j] = 0.f;
    float lsum = 0.f;

    // prologue: stage tiles 0 and 1 (6 loads each per wave)
    stage48(KV, start, (char*)&kv[0][0], w, lane);
    if (cnt > 1) stage48(KV, start + 1, (char*)&kv[1][0], w, lane);

    int bufc = 0;                                  // kt % 3
    for (int kt = 0; kt < cnt; kt++) {
        // ---- tile boundary: counted wait (tile kt's batch complete) ----
        if (kt + 1 < cnt) { asm volatile("s_waitcnt vmcnt(6)" ::: "memory"); }
        else              { asm volatile("s_waitcnt vmcnt(0)" ::: "memory"); }
        __builtin_amdgcn_s_barrier();

        const short* kb = &kv[bufc][0];
        // issue staging for tile kt+2 into buf (kt+2)%3 — lives across barriers
        const int bufn = bufc + 2 >= 3 ? bufc - 1 : bufc + 2;
        if (kt + 2 < cnt)
            stage48(KV, start + kt + 2, (char*)&kv[bufn][0], w, lane);

        #pragma unroll
        for (int n2 = 0; n2 < 2; n2++) {
            // ---- S' = K Q: 32 keys x 32 queries (f16, single-term) ----
            facc16 S;
            #pragma unroll
            for (int j = 0; j < 16; j++) S[j] = 0.f;
            __builtin_amdgcn_s_setprio(1);
            #pragma unroll
            for (int t = 0; t < 12; t++) {
                hfrag kf = *(const hfrag*)(const void*)(kb + (n2 * 12 + t) * 512 + lane * 8);
                S = __builtin_amdgcn_mfma_f32_32x32x16_f16(kf, qf[t], S, 0, 0, 0);
            }
            __builtin_amdgcn_s_setprio(0);
            // S' layout: key = (j&3)+8*(j>>2)+4*h (lane-local), q = l32

            // ---- P = 2^(S' - M0L); tree-sum; pack (no cross-lane moves) ----
            float p[16];
            #pragma unroll
            for (int j = 0; j < 16; j++) p[j] = exp2_raw(S[j] - M0L);
            lsum += (((p[0]+p[1])+(p[2]+p[3]))+((p[4]+p[5])+(p[6]+p[7])))
                  + (((p[8]+p[9])+(p[10]+p[11]))+((p[12]+p[13])+(p[14]+p[15])));
            int cp[8];
            #pragma unroll
            for (int a = 0; a < 8; a++) cp[a] = cvtpk_bf16(p[2 * a], p[2 * a + 1]);

            // ---- O^T += V^T P  (two 16-key groups; V rows pre-permuted) ----
            #pragma unroll
            for (int T = 0; T < 2; T++) {
                bfrag pf = words_to_frag(cp[4*T], cp[4*T+1], cp[4*T+2], cp[4*T+3]);
                const int ksp = n2 * 2 + T;
                __builtin_amdgcn_s_setprio(1);
                #pragma unroll
                for (int cb = 0; cb < 6; cb++) {
                    bfrag vf = *(const bfrag*)(const void*)(kb + 12288 + (ksp * 6 + cb) * 512 + lane * 8);
                    O[cb] = __builtin_amdgcn_mfma_f32_32x32x16_bf16(vf, pf, O[cb], 0, 0, 0);
                }
                __builtin_amdgcn_s_setprio(0);
            }
        }
        bufc = bufc + 1 >= 3 ? 0 : bufc + 1;
    }

    // ---- epilogue: Opart[ks][q][c] (bf16, unnormalized) + l per query ----
    const int q0 = qt * 256 + w * 32 + l32;
    short* row = Opart + ((size_t)ks * NQ + q0) * NC;
    #pragma unroll
    for (int cb = 0; cb < 6; cb++) {
        #pragma unroll
        for (int g = 0; g < 4; g++) {
            const int c0 = cb * 32 + 8 * g + 4 * h;
            sfrag4 s4;
            #pragma unroll
            for (int r = 0; r < 4; r++) s4[r] = f2bf(O[cb][4 * g + r]);
            *(sfrag4*)(void*)(row + c0) = s4;
        }
    }
    float lt = lsum + __shfl_xor(lsum, 32);
    if (h == 0) l_ws[(size_t)ks * NQ + q0] = lt;
}

// ---------------------------------------------------------------------------
// Combine: sum KS partials (common scale), normalize, transpose via LDS,
// fused epilogue out = refined*w5 + ctx.  288 blocks x 32 queries.
// ---------------------------------------------------------------------------
__global__ __launch_bounds__(256) void InterGate_combine(
    const short* __restrict__ Opart, const float* __restrict__ l_ws,
    const float* __restrict__ refined, const float* __restrict__ w5,
    float* __restrict__ out, int KS)
{
    __shared__ float ctx[32][193];
    __shared__ float sInv[32];
    const int qt = blockIdx.x, tid = threadIdx.x;

    if (tid < 32) {
        const int q = qt * 32 + tid;
        float L = 0.f;
        for (int ks = 0; ks < KS; ks++) L += l_ws[(size_t)ks * NQ + q];
        sInv[tid] = 1.f / L;
    }
    __syncthreads();

    for (int u = tid; u < 768; u += 256) {
        const int ql = u / 24, c0 = (u % 24) * 8;
        float acc[8] = {0.f, 0.f, 0.f, 0.f, 0.f, 0.f, 0.f, 0.f};
        for (int ks = 0; ks < KS; ks++) {
            bfrag pk = *(const bfrag*)(const void*)&Opart[((size_t)ks * NQ + qt * 32 + ql) * NC + c0];
            #pragma unroll
            for (int j = 0; j < 8; j++) acc[j] += bf2f(pk[j]);
        }
        const float inv = sInv[ql];
        #pragma unroll
        for (int j = 0; j < 8; j++) ctx[ql][c0 + j] = acc[j] * inv;
    }
    __syncthreads();

    for (int u = tid; u < 6144; u += 256) {
        const int c = u / 32, qx = u % 32;
        size_t o = (size_t)c * NQ + qt * 32 + qx;
        out[o] = refined[o] * w5[o] + ctx[qx][c];
    }
}

// ---------------------------------------------------------------------------
extern "C" void kernel_launch(void* const* d_in, const int* in_sizes, int n_in,
                              void* d_out, int out_size, void* d_ws, size_t ws_size,
                              hipStream_t stream)
{
    (void)in_sizes; (void)n_in; (void)out_size;
    const float* latent  = (const float*)d_in[0];
    const float* refined = (const float*)d_in[1];
    const float* w4      = (const float*)d_in[2];
    const float* w5      = (const float*)d_in[3];
    float* out = (float*)d_out;

    short* Qf = (short*)d_ws;
    short* KV = Qf + FR;                     // 2*FR shorts (K|V per 64-key group)
    const size_t basebytes = (size_t)3 * FR * 2;

    // KS=7 -> grid 252 (1 block/CU); fallbacks if ws is small
    const int opts[4] = {7, 4, 2, 1};
    int KS = 0;
    for (int i = 0; i < 4; i++) {
        size_t need = basebytes + (size_t)opts[i] * ((size_t)NQ * NC * 2 + (size_t)NQ * 4);
        if (need <= ws_size) { KS = opts[i]; break; }
    }
    if (KS == 0) return;

    short* Opart = (short*)((char*)d_ws + basebytes);
    float* l_ws  = (float*)((char*)d_ws + basebytes + (size_t)KS * NQ * NC * 2);

    InterGate_prep<<<2592, 256, 0, stream>>>(latent, refined, w4, Qf, KV);
    dim3 fg(36, KS);
    InterGate_flash<<<fg, 512, 0, stream>>>(Qf, KV, Opart, l_ws, KS);
    InterGate_combine<<<288, 256, 0, stream>>>(Opart, l_ws, refined, w5, out, KS);
}